// Round 1
// baseline (5600.527 us; speedup 1.0000x reference)
//
#include <hip/hip_runtime.h>

#define DD 64

// ---- degree: deg[src[e]] += 1 ----
__global__ void deg_kernel(const int* __restrict__ src, float* __restrict__ deg, int E) {
    int e = blockIdx.x * blockDim.x + threadIdx.x;
    if (e < E) atomicAdd(&deg[src[e]], 1.0f);
}

// ---- dis = deg>0 ? rsqrt(deg) : 0 (in place) ----
__global__ void dis_kernel(float* __restrict__ deg, int N) {
    int n = blockIdx.x * blockDim.x + threadIdx.x;
    if (n < N) {
        float d = deg[n];
        deg[n] = (d > 0.0f) ? rsqrtf(d) : 0.0f;
    }
}

// ---- norm[e] = -dis[src]*dis[dst] ----
__global__ void norm_kernel(const int* __restrict__ src, const int* __restrict__ dst,
                            const float* __restrict__ dis, float* __restrict__ norm, int E) {
    int e = blockIdx.x * blockDim.x + threadIdx.x;
    if (e < E) norm[e] = -dis[src[e]] * dis[dst[e]];
}

// ---- scatter prop: out[dst] += scale*norm[e]*h[src], 16 threads/edge (float4 each) ----
__global__ void prop_kernel(const int* __restrict__ src, const int* __restrict__ dst,
                            const float* __restrict__ norm, const float* __restrict__ h,
                            float* __restrict__ out, float scale, int E) {
    long long tid = (long long)blockIdx.x * blockDim.x + threadIdx.x;
    long long e = tid >> 4;
    int c = (int)(tid & 15);
    if (e < E) {
        int s = src[e];
        int d = dst[e];
        float w = scale * norm[e];
        float4 v = *reinterpret_cast<const float4*>(h + (long long)s * DD + c * 4);
        float* o = out + (long long)d * DD + c * 4;
        atomicAdd(o + 0, w * v.x);
        atomicAdd(o + 1, w * v.y);
        atomicAdd(o + 2, w * v.z);
        atomicAdd(o + 3, w * v.w);
    }
}

// ---- dst[i] = -src[i] ----
__global__ void copyneg_kernel(float* __restrict__ dst, const float* __restrict__ src, long long n) {
    long long i = (long long)blockIdx.x * blockDim.x + threadIdx.x;
    if (i < n) dst[i] = -src[i];
}

// ---- buf[i] = -buf[i] ----
__global__ void negip_kernel(float* __restrict__ buf, long long n) {
    long long i = (long long)blockIdx.x * blockDim.x + threadIdx.x;
    if (i < n) buf[i] = -buf[i];
}

// ---- out[n][d] (+)= sum_j Tx[n][j]*Wk[j][d]  (+ b[d] when init) ----
__global__ __launch_bounds__(256) void gemm_kernel(const float* __restrict__ Tx,
                                                   const float* __restrict__ Wk,
                                                   const float* __restrict__ b,
                                                   float* __restrict__ out, int N, int init) {
    __shared__ float Ws[DD][DD];   // 16 KB
    __shared__ float rows[4][DD + 1];
    int t = threadIdx.x;
    for (int i = t; i < DD * DD; i += 256) Ws[i >> 6][i & 63] = Wk[i];
    int nl = t >> 6;
    int d = t & 63;
    long long node = (long long)blockIdx.x * 4 + nl;
    if (node < N) rows[nl][d] = Tx[node * DD + d];
    __syncthreads();
    if (node >= N) return;
    float acc = 0.0f;
    #pragma unroll
    for (int j = 0; j < DD; ++j) acc += rows[nl][j] * Ws[j][d];
    long long o = node * DD + d;
    out[o] = (init ? b[d] : out[o]) + acc;
}

extern "C" void kernel_launch(void* const* d_in, const int* in_sizes, int n_in,
                              void* d_out, int out_size, void* d_ws, size_t ws_size,
                              hipStream_t stream) {
    const float* x  = (const float*)d_in[0];
    const int*   ei = (const int*)d_in[1];
    const float* W  = (const float*)d_in[2];
    const float* b  = (const float*)d_in[3];
    float* out = (float*)d_out;

    const int N = in_sizes[0] / DD;
    const int E = in_sizes[1] / 2;
    const int K = in_sizes[2] / (DD * DD);

    const int* src = ei;
    const int* dst = ei + E;

    float* ws   = (float*)d_ws;
    float* dis  = ws;                       // N
    float* norm = dis + N;                  // E
    float* B1   = norm + E;                 // N*64
    float* B2   = B1 + (long long)N * DD;   // N*64

    const long long ND = (long long)N * DD;

    // degrees -> dis
    hipMemsetAsync(dis, 0, (size_t)N * sizeof(float), stream);
    deg_kernel<<<(E + 255) / 256, 256, 0, stream>>>(src, dis, E);
    dis_kernel<<<(N + 255) / 256, 256, 0, stream>>>(dis, N);
    norm_kernel<<<(E + 255) / 256, 256, 0, stream>>>(src, dst, dis, norm, E);

    const int gemm_grid = (N + 3) / 4;
    const long long prop_threads = (long long)E * 16;
    const int prop_grid = (int)((prop_threads + 255) / 256);
    const int nd_grid = (int)((ND + 255) / 256);

    // k=0: out = x @ W0 + b
    gemm_kernel<<<gemm_grid, 256, 0, stream>>>(x, W, b, out, N, 1);

    // k=1: Tx1 = prop(x) -> B1 ; out += Tx1 @ W1
    hipMemsetAsync(B1, 0, (size_t)ND * sizeof(float), stream);
    prop_kernel<<<prop_grid, 256, 0, stream>>>(src, dst, norm, x, B1, 1.0f, E);
    gemm_kernel<<<gemm_grid, 256, 0, stream>>>(B1, W + DD * DD, b, out, N, 0);

    // k>=2: Txk = 2*prop(Tx1) - Tx0 (fused: target init = -Tx0, scatter 2*norm*h)
    float* t0 = nullptr;   // nullptr means x
    float* t1 = B1;
    float* tg = B2;
    for (int k = 2; k < K; ++k) {
        if (t0 == nullptr) {
            copyneg_kernel<<<nd_grid, 256, 0, stream>>>(tg, x, ND);
        } else {
            // tg aliases t0 here by construction: in-place negate
            negip_kernel<<<nd_grid, 256, 0, stream>>>(tg, ND);
        }
        prop_kernel<<<prop_grid, 256, 0, stream>>>(src, dst, norm, t1, tg, 2.0f, E);
        gemm_kernel<<<gemm_grid, 256, 0, stream>>>(tg, W + (long long)k * DD * DD, b, out, N, 0);
        float* old_t1 = t1;
        t0 = t1;
        t1 = tg;
        tg = old_t1;
    }
}

// Round 3
// 818.842 us; speedup vs baseline: 6.8396x; 6.8396x over previous
//
#include <hip/hip_runtime.h>

#define DD 64

// ---- degree over src (float, for dis) + count over dst (int, for CSR) ----
__global__ void degcnt_kernel(const int* __restrict__ src, const int* __restrict__ dst,
                              float* __restrict__ deg, int* __restrict__ cnt, int E) {
    int e = blockIdx.x * blockDim.x + threadIdx.x;
    if (e < E) {
        atomicAdd(&deg[src[e]], 1.0f);
        atomicAdd(&cnt[dst[e]], 1);
    }
}

// ---- dis = deg>0 ? rsqrt(deg) : 0 (in place) ----
__global__ void dis_kernel(float* __restrict__ deg, int N) {
    int n = blockIdx.x * blockDim.x + threadIdx.x;
    if (n < N) {
        float d = deg[n];
        deg[n] = (d > 0.0f) ? rsqrtf(d) : 0.0f;
    }
}

// ---- scan step 1: per-block (1024) exclusive scan of cnt -> rowptr; block sums -> bsum ----
__global__ __launch_bounds__(1024) void scan1_kernel(const int* __restrict__ cnt,
                                                     int* __restrict__ rowptr,
                                                     int* __restrict__ bsum, int N) {
    __shared__ int tmp[1024];
    int t = threadIdx.x;
    int g = blockIdx.x * 1024 + t;
    int v = (g < N) ? cnt[g] : 0;
    tmp[t] = v;
    __syncthreads();
    for (int off = 1; off < 1024; off <<= 1) {
        int a = (t >= off) ? tmp[t - off] : 0;
        __syncthreads();
        tmp[t] += a;
        __syncthreads();
    }
    if (g < N) rowptr[g] = tmp[t] - v;   // exclusive within block
    if (t == 1023) bsum[blockIdx.x] = tmp[1023];
}

// ---- scan step 2: one block, exclusive scan of bsum (nb <= 128) in place ----
__global__ __launch_bounds__(128) void scan2_kernel(int* __restrict__ data, int n) {
    __shared__ int tmp[128];
    int t = threadIdx.x;
    int v = (t < n) ? data[t] : 0;
    tmp[t] = v;
    __syncthreads();
    for (int off = 1; off < 128; off <<= 1) {
        int a = (t >= off) ? tmp[t - off] : 0;
        __syncthreads();
        tmp[t] += a;
        __syncthreads();
    }
    if (t < n) data[t] = tmp[t] - v;
}

// ---- scan step 3: add block offsets; set rowptr[N]=E ----
__global__ void scan3_kernel(int* __restrict__ rowptr, const int* __restrict__ bsum,
                             int N, int E) {
    int g = blockIdx.x * blockDim.x + threadIdx.x;
    if (g < N) rowptr[g] += bsum[g >> 10];
    if (g == 0) rowptr[N] = E;
}

// ---- CSR fill: adj_s[pos]=src, adj_w[pos]=-dis[src]*dis[dst] ----
__global__ void fill_kernel(const int* __restrict__ src, const int* __restrict__ dst,
                            const float* __restrict__ dis, const int* __restrict__ rowptr,
                            int* __restrict__ fillc, int* __restrict__ adj_s,
                            float* __restrict__ adj_w, int E) {
    int e = blockIdx.x * blockDim.x + threadIdx.x;
    if (e < E) {
        int s = src[e], d = dst[e];
        int pos = rowptr[d] + atomicAdd(&fillc[d], 1);
        adj_s[pos] = s;
        adj_w[pos] = -dis[s] * dis[d];
    }
}

// ---- fused: Txk = scale*gather(h) - tx0 ; txout = Txk ;
//      out (+)= Txk@Wk  [+ h@W0 + b when W0 != null, no out read] ----
// one wave per node, lane = column d.
// NOTE: txout may alias tx0 (each thread reads tx0 only at its own index,
// before writing) — so NO __restrict__ on these two.
__global__ __launch_bounds__(256) void prop_fused_kernel(
        const int* __restrict__ rowptr, const int* __restrict__ adj_s,
        const float* __restrict__ adj_w, const float* __restrict__ h,
        const float* tx0, const float* __restrict__ W0,
        const float* __restrict__ Wk, const float* __restrict__ bias,
        float* txout, float* __restrict__ out,
        float scale, int N) {
    __shared__ float rows[4][DD];
    __shared__ float xrow[4][DD];
    int t = threadIdx.x;
    int nl = t >> 6;           // wave id in block
    int d = t & 63;            // column
    int node = blockIdx.x * 4 + nl;
    if (node >= N) return;
    long long base = (long long)node * DD;

    int beg = rowptr[node], end = rowptr[node + 1];
    float acc = 0.0f;
    int j = beg;
    for (; j + 1 < end; j += 2) {
        int s0 = adj_s[j], s1 = adj_s[j + 1];
        float w0 = adj_w[j], w1 = adj_w[j + 1];
        float v0 = h[(long long)s0 * DD + d];
        float v1 = h[(long long)s1 * DD + d];
        acc += w0 * v0;
        acc += w1 * v1;
    }
    if (j < end) {
        int s0 = adj_s[j];
        acc += adj_w[j] * h[(long long)s0 * DD + d];
    }

    float v = scale * acc - (tx0 ? tx0[base + d] : 0.0f);
    txout[base + d] = v;
    rows[nl][d] = v;                       // wave-private slice
    if (W0) xrow[nl][d] = h[base + d];     // h == x on the init pass
    __builtin_amdgcn_wave_barrier();       // pin LDS write->read ordering in-wave

    float o;
    if (W0) {
        o = bias[d];
        #pragma unroll
        for (int jj = 0; jj < DD; ++jj) {
            o += xrow[nl][jj] * W0[jj * DD + d];
            o += rows[nl][jj] * Wk[jj * DD + d];
        }
    } else {
        o = out[base + d];
        #pragma unroll
        for (int jj = 0; jj < DD; ++jj) o += rows[nl][jj] * Wk[jj * DD + d];
    }
    out[base + d] = o;
}

extern "C" void kernel_launch(void* const* d_in, const int* in_sizes, int n_in,
                              void* d_out, int out_size, void* d_ws, size_t ws_size,
                              hipStream_t stream) {
    const float* x  = (const float*)d_in[0];
    const int*   ei = (const int*)d_in[1];
    const float* W  = (const float*)d_in[2];
    const float* b  = (const float*)d_in[3];
    float* out = (float*)d_out;

    const int N = in_sizes[0] / DD;
    const int E = in_sizes[1] / 2;
    const int K = in_sizes[2] / (DD * DD);
    const long long ND = (long long)N * DD;

    const int* src = ei;
    const int* dst = ei + E;

    float* ws    = (float*)d_ws;
    float* dis   = ws;                          // N floats
    int*   cnt   = (int*)(dis + N);             // N
    int*   fillc = cnt + N;                     // N
    int*   rowptr= fillc + N;                   // N+1
    int*   bsum  = rowptr + N + 1;              // 128
    int*   adj_s = bsum + 128;                  // E
    float* adj_w = (float*)(adj_s + E);         // E
    float* B1    = adj_w + E;                   // ND
    float* B2    = B1 + ND;                     // ND

    // zero dis, cnt, fillc in one memset (contiguous)
    hipMemsetAsync(dis, 0, (size_t)(3 * N) * sizeof(float), stream);

    degcnt_kernel<<<(E + 255) / 256, 256, 0, stream>>>(src, dst, dis, cnt, E);
    dis_kernel<<<(N + 255) / 256, 256, 0, stream>>>(dis, N);

    const int nb = (N + 1023) / 1024;           // <= 128 required
    scan1_kernel<<<nb, 1024, 0, stream>>>(cnt, rowptr, bsum, N);
    scan2_kernel<<<1, 128, 0, stream>>>(bsum, nb);
    scan3_kernel<<<(N + 255) / 256, 256, 0, stream>>>(rowptr, bsum, N, E);
    fill_kernel<<<(E + 255) / 256, 256, 0, stream>>>(src, dst, dis, rowptr, fillc,
                                                     adj_s, adj_w, E);

    const int pgrid = (N + 3) / 4;

    // k=0 + k=1 fused: out = b + x@W0 + Tx1@W1 ; B1 = Tx1 = prop(x)
    prop_fused_kernel<<<pgrid, 256, 0, stream>>>(rowptr, adj_s, adj_w, x,
                                                 nullptr, W, W + DD * DD, b,
                                                 B1, out, 1.0f, N);

    // k>=2: Txk = 2*prop(Tx1) - Tx0 ; out += Txk@Wk
    // Rotation invariant: target always aliases the NEXT tx0 (safe: tx0 is
    // read only at the owning thread's index before the write); never aliases h.
    const float* t0 = x;
    float* t1 = B1;
    float* tg = B2;
    for (int k = 2; k < K; ++k) {
        prop_fused_kernel<<<pgrid, 256, 0, stream>>>(rowptr, adj_s, adj_w, t1,
                                                     t0, nullptr,
                                                     W + (long long)k * DD * DD, b,
                                                     tg, out, 2.0f, N);
        const float* nt0 = t1;   // Tx_{k-1}
        float* nt1 = tg;         // Tx_k
        tg = (float*)nt0;        // next target aliases next tx0
        t0 = nt0;
        t1 = nt1;
    }
}

// Round 4
// 694.322 us; speedup vs baseline: 8.0662x; 1.1793x over previous
//
#include <hip/hip_runtime.h>

#define DD 64

// ---- degree over src (float, for dis) + count over dst (int, for CSR) ----
__global__ void degcnt_kernel(const int* __restrict__ src, const int* __restrict__ dst,
                              float* __restrict__ deg, int* __restrict__ cnt, int E) {
    int e = blockIdx.x * blockDim.x + threadIdx.x;
    if (e < E) {
        atomicAdd(&deg[src[e]], 1.0f);
        atomicAdd(&cnt[dst[e]], 1);
    }
}

// ---- dis = deg>0 ? rsqrt(deg) : 0 (in place) ----
__global__ void dis_kernel(float* __restrict__ deg, int N) {
    int n = blockIdx.x * blockDim.x + threadIdx.x;
    if (n < N) {
        float d = deg[n];
        deg[n] = (d > 0.0f) ? rsqrtf(d) : 0.0f;
    }
}

// ---- scan step 1: per-block (1024) exclusive scan of cnt -> rowptr; block sums -> bsum ----
__global__ __launch_bounds__(1024) void scan1_kernel(const int* __restrict__ cnt,
                                                     int* __restrict__ rowptr,
                                                     int* __restrict__ bsum, int N) {
    __shared__ int tmp[1024];
    int t = threadIdx.x;
    int g = blockIdx.x * 1024 + t;
    int v = (g < N) ? cnt[g] : 0;
    tmp[t] = v;
    __syncthreads();
    for (int off = 1; off < 1024; off <<= 1) {
        int a = (t >= off) ? tmp[t - off] : 0;
        __syncthreads();
        tmp[t] += a;
        __syncthreads();
    }
    if (g < N) rowptr[g] = tmp[t] - v;   // exclusive within block
    if (t == 1023) bsum[blockIdx.x] = tmp[1023];
}

// ---- scan step 2: one block, exclusive scan of bsum (nb <= 128) in place ----
__global__ __launch_bounds__(128) void scan2_kernel(int* __restrict__ data, int n) {
    __shared__ int tmp[128];
    int t = threadIdx.x;
    int v = (t < n) ? data[t] : 0;
    tmp[t] = v;
    __syncthreads();
    for (int off = 1; off < 128; off <<= 1) {
        int a = (t >= off) ? tmp[t - off] : 0;
        __syncthreads();
        tmp[t] += a;
        __syncthreads();
    }
    if (t < n) data[t] = tmp[t] - v;
}

// ---- scan step 3: add block offsets; set rowptr[N]=E ----
__global__ void scan3_kernel(int* __restrict__ rowptr, const int* __restrict__ bsum,
                             int N, int E) {
    int g = blockIdx.x * blockDim.x + threadIdx.x;
    if (g < N) rowptr[g] += bsum[g >> 10];
    if (g == 0) rowptr[N] = E;
}

// ---- CSR fill: adj[pos] = (src, -dis[src]*dis[dst]) packed ----
__global__ void fill_kernel(const int* __restrict__ src, const int* __restrict__ dst,
                            const float* __restrict__ dis, const int* __restrict__ rowptr,
                            int* __restrict__ fillc, int2* __restrict__ adj, int E) {
    int e = blockIdx.x * blockDim.x + threadIdx.x;
    if (e < E) {
        int s = src[e], d = dst[e];
        int pos = rowptr[d] + atomicAdd(&fillc[d], 1);
        adj[pos] = make_int2(s, __float_as_int(-dis[s] * dis[d]));
    }
}

// ---- fused: Txk = scale*gather(h) - tx0 ; txout = Txk ;
//      out (+)= Txk@Wk  [+ h@W0 + b when W0 != null, no out read] ----
// one wave per node; gather phase: 4 edge-slots x 16 lanes (float4 quarter-rows),
// unroll 2 -> 8 rows in flight per wave. Epilogue: lane = column d.
// NOTE: txout may alias tx0 (own-index read-before-write) — no __restrict__ there.
__global__ __launch_bounds__(256) void prop_fused_kernel(
        const int* __restrict__ rowptr, const int2* __restrict__ adj,
        const float* __restrict__ h,
        const float* tx0, const float* __restrict__ W0,
        const float* __restrict__ Wk, const float* __restrict__ bias,
        float* txout, float* __restrict__ out,
        float scale, int N) {
    __shared__ float rows[4][DD];
    __shared__ float xrow[4][DD];
    int t = threadIdx.x;
    int nl = t >> 6;           // wave id in block
    int lane = t & 63;
    int eg = lane >> 4;        // edge slot 0..3
    int q = lane & 15;         // quarter-row: columns 4q..4q+3
    int node = blockIdx.x * 4 + nl;
    if (node >= N) return;
    long long base = (long long)node * DD;

    const float4* h4 = reinterpret_cast<const float4*>(h);

    int beg = rowptr[node], end = rowptr[node + 1];
    float4 acc = make_float4(0.f, 0.f, 0.f, 0.f);
    int j = beg + eg;
    for (; j + 4 < end; j += 8) {
        int2 e0 = adj[j];
        int2 e1 = adj[j + 4];
        float4 v0 = h4[(long long)e0.x * 16 + q];
        float4 v1 = h4[(long long)e1.x * 16 + q];
        float w0 = __int_as_float(e0.y);
        float w1 = __int_as_float(e1.y);
        acc.x += w0 * v0.x + w1 * v1.x;
        acc.y += w0 * v0.y + w1 * v1.y;
        acc.z += w0 * v0.z + w1 * v1.z;
        acc.w += w0 * v0.w + w1 * v1.w;
    }
    if (j < end) {
        int2 e0 = adj[j];
        float4 v0 = h4[(long long)e0.x * 16 + q];
        float w0 = __int_as_float(e0.y);
        acc.x += w0 * v0.x;
        acc.y += w0 * v0.y;
        acc.z += w0 * v0.z;
        acc.w += w0 * v0.w;
    }
    // reduce across the 4 edge-slot groups (lanes q, q+16, q+32, q+48)
    #pragma unroll
    for (int m = 16; m < 64; m <<= 1) {
        acc.x += __shfl_xor(acc.x, m, 64);
        acc.y += __shfl_xor(acc.y, m, 64);
        acc.z += __shfl_xor(acc.z, m, 64);
        acc.w += __shfl_xor(acc.w, m, 64);
    }

    if (eg == 0) {
        float4 t0v = make_float4(0.f, 0.f, 0.f, 0.f);
        if (tx0) t0v = *reinterpret_cast<const float4*>(tx0 + base + q * 4);
        float4 v;
        v.x = scale * acc.x - t0v.x;
        v.y = scale * acc.y - t0v.y;
        v.z = scale * acc.z - t0v.z;
        v.w = scale * acc.w - t0v.w;
        *reinterpret_cast<float4*>(txout + base + q * 4) = v;
        *reinterpret_cast<float4*>(&rows[nl][q * 4]) = v;
    }
    if (W0) xrow[nl][lane] = h[base + lane];   // h == x on the init pass
    __builtin_amdgcn_wave_barrier();           // pin LDS write->read ordering in-wave

    float o;
    if (W0) {
        o = bias[lane];
        #pragma unroll
        for (int jj = 0; jj < DD; ++jj) {
            o += xrow[nl][jj] * W0[jj * DD + lane];
            o += rows[nl][jj] * Wk[jj * DD + lane];
        }
    } else {
        o = out[base + lane];
        #pragma unroll
        for (int jj = 0; jj < DD; ++jj) o += rows[nl][jj] * Wk[jj * DD + lane];
    }
    out[base + lane] = o;
}

extern "C" void kernel_launch(void* const* d_in, const int* in_sizes, int n_in,
                              void* d_out, int out_size, void* d_ws, size_t ws_size,
                              hipStream_t stream) {
    const float* x  = (const float*)d_in[0];
    const int*   ei = (const int*)d_in[1];
    const float* W  = (const float*)d_in[2];
    const float* b  = (const float*)d_in[3];
    float* out = (float*)d_out;

    const int N = in_sizes[0] / DD;
    const int E = in_sizes[1] / 2;
    const int K = in_sizes[2] / (DD * DD);
    const long long ND = (long long)N * DD;

    const int* src = ei;
    const int* dst = ei + E;

    float* ws    = (float*)d_ws;
    float* dis   = ws;                          // N floats
    int*   cnt   = (int*)(dis + N);             // N
    int*   fillc = cnt + N;                     // N
    int*   rowptr= fillc + N;                   // N+1
    int*   bsum  = rowptr + N + 1;              // 128
    int2*  adj   = (int2*)(bsum + 128);         // E (8B each, 8B-aligned)
    float* B1    = (float*)(adj + E);           // ND
    float* B2    = B1 + ND;                     // ND

    // zero dis, cnt, fillc in one memset (contiguous)
    hipMemsetAsync(dis, 0, (size_t)(3 * N) * sizeof(float), stream);

    degcnt_kernel<<<(E + 255) / 256, 256, 0, stream>>>(src, dst, dis, cnt, E);
    dis_kernel<<<(N + 255) / 256, 256, 0, stream>>>(dis, N);

    const int nb = (N + 1023) / 1024;           // <= 128 required
    scan1_kernel<<<nb, 1024, 0, stream>>>(cnt, rowptr, bsum, N);
    scan2_kernel<<<1, 128, 0, stream>>>(bsum, nb);
    scan3_kernel<<<(N + 255) / 256, 256, 0, stream>>>(rowptr, bsum, N, E);
    fill_kernel<<<(E + 255) / 256, 256, 0, stream>>>(src, dst, dis, rowptr, fillc,
                                                     adj, E);

    const int pgrid = (N + 3) / 4;

    // k=0 + k=1 fused: out = b + x@W0 + Tx1@W1 ; B1 = Tx1 = prop(x)
    prop_fused_kernel<<<pgrid, 256, 0, stream>>>(rowptr, adj, x,
                                                 nullptr, W, W + DD * DD, b,
                                                 B1, out, 1.0f, N);

    // k>=2: Txk = 2*prop(Tx1) - Tx0 ; out += Txk@Wk
    // Rotation invariant: target always aliases the NEXT tx0 (safe: tx0 is
    // read only at the owning thread's index before the write); never aliases h.
    const float* t0 = x;
    float* t1 = B1;
    float* tg = B2;
    for (int k = 2; k < K; ++k) {
        prop_fused_kernel<<<pgrid, 256, 0, stream>>>(rowptr, adj, t1,
                                                     t0, nullptr,
                                                     W + (long long)k * DD * DD, b,
                                                     tg, out, 2.0f, N);
        const float* nt0 = t1;   // Tx_{k-1}
        float* nt1 = tg;         // Tx_k
        tg = (float*)nt0;        // next target aliases next tx0
        t0 = nt0;
        t1 = nt1;
    }
}

// Round 5
// 694.083 us; speedup vs baseline: 8.0690x; 1.0003x over previous
//
#include <hip/hip_runtime.h>

#define DD 64
#define NPW 4   // nodes per wave; 4 waves/block -> 16 nodes/block

// ---- degree over src (float, for dis) + count over dst (int, for CSR) ----
__global__ void degcnt_kernel(const int* __restrict__ src, const int* __restrict__ dst,
                              float* __restrict__ deg, int* __restrict__ cnt, int E) {
    int e = blockIdx.x * blockDim.x + threadIdx.x;
    if (e < E) {
        atomicAdd(&deg[src[e]], 1.0f);
        atomicAdd(&cnt[dst[e]], 1);
    }
}

// ---- dis = deg>0 ? rsqrt(deg) : 0 (in place) ----
__global__ void dis_kernel(float* __restrict__ deg, int N) {
    int n = blockIdx.x * blockDim.x + threadIdx.x;
    if (n < N) {
        float d = deg[n];
        deg[n] = (d > 0.0f) ? rsqrtf(d) : 0.0f;
    }
}

// ---- scan step 1: per-block (1024) exclusive scan of cnt -> rowptr; block sums -> bsum ----
__global__ __launch_bounds__(1024) void scan1_kernel(const int* __restrict__ cnt,
                                                     int* __restrict__ rowptr,
                                                     int* __restrict__ bsum, int N) {
    __shared__ int tmp[1024];
    int t = threadIdx.x;
    int g = blockIdx.x * 1024 + t;
    int v = (g < N) ? cnt[g] : 0;
    tmp[t] = v;
    __syncthreads();
    for (int off = 1; off < 1024; off <<= 1) {
        int a = (t >= off) ? tmp[t - off] : 0;
        __syncthreads();
        tmp[t] += a;
        __syncthreads();
    }
    if (g < N) rowptr[g] = tmp[t] - v;   // exclusive within block
    if (t == 1023) bsum[blockIdx.x] = tmp[1023];
}

// ---- scan step 2: one block, exclusive scan of bsum (nb <= 128) in place ----
__global__ __launch_bounds__(128) void scan2_kernel(int* __restrict__ data, int n) {
    __shared__ int tmp[128];
    int t = threadIdx.x;
    int v = (t < n) ? data[t] : 0;
    tmp[t] = v;
    __syncthreads();
    for (int off = 1; off < 128; off <<= 1) {
        int a = (t >= off) ? tmp[t - off] : 0;
        __syncthreads();
        tmp[t] += a;
        __syncthreads();
    }
    if (t < n) data[t] = tmp[t] - v;
}

// ---- scan step 3: add block offsets; set rowptr[N]=E ----
__global__ void scan3_kernel(int* __restrict__ rowptr, const int* __restrict__ bsum,
                             int N, int E) {
    int g = blockIdx.x * blockDim.x + threadIdx.x;
    if (g < N) rowptr[g] += bsum[g >> 10];
    if (g == 0) rowptr[N] = E;
}

// ---- CSR fill: adj[pos] = (src, -dis[src]*dis[dst]) packed ----
__global__ void fill_kernel(const int* __restrict__ src, const int* __restrict__ dst,
                            const float* __restrict__ dis, const int* __restrict__ rowptr,
                            int* __restrict__ fillc, int2* __restrict__ adj, int E) {
    int e = blockIdx.x * blockDim.x + threadIdx.x;
    if (e < E) {
        int s = src[e], d = dst[e];
        int pos = rowptr[d] + atomicAdd(&fillc[d], 1);
        adj[pos] = make_int2(s, __float_as_int(-dis[s] * dis[d]));
    }
}

// ---- fused: Txk = scale*gather(h) - tx0 ; txout = Txk (optional) ;
//      out (+)= Txk@Wk  [+ h@W0 + b when W0 != null, no out read] ----
// 4 waves/block, NPW nodes per wave. Wk (and W0) staged in LDS per block.
// Gather: 4 edge-slots x 16 lanes (float4 quarter-rows), unroll 2.
// NOTE: txout may alias tx0 (own-index read-before-write) — no __restrict__ there.
__global__ __launch_bounds__(256) void prop_fused_kernel(
        const int* __restrict__ rowptr, const int2* __restrict__ adj,
        const float* __restrict__ h,
        const float* tx0, const float* __restrict__ W0,
        const float* __restrict__ Wk, const float* __restrict__ bias,
        float* txout, float* __restrict__ out,
        float scale, int N) {
    extern __shared__ float smem[];            // Ws[4096] (+ W0s[4096] on init pass)
    float* Ws  = smem;
    float* W0s = smem + DD * DD;
    __shared__ float rows[4][DD];
    __shared__ float xrow[4][DD];

    int t = threadIdx.x;
    // stage Wk (and W0) into LDS: 1024 float4, 4 per thread
    {
        const float4* s4 = reinterpret_cast<const float4*>(Wk);
        float4* d4 = reinterpret_cast<float4*>(Ws);
        #pragma unroll
        for (int i = 0; i < 4; ++i) d4[t + 256 * i] = s4[t + 256 * i];
        if (W0) {
            const float4* s04 = reinterpret_cast<const float4*>(W0);
            float4* d04 = reinterpret_cast<float4*>(W0s);
            #pragma unroll
            for (int i = 0; i < 4; ++i) d04[t + 256 * i] = s04[t + 256 * i];
        }
    }
    __syncthreads();

    int nl = t >> 6;           // wave id in block
    int lane = t & 63;
    int eg = lane >> 4;        // edge slot 0..3
    int q = lane & 15;         // quarter-row: columns 4q..4q+3
    const float4* h4 = reinterpret_cast<const float4*>(h);

    int node0 = (blockIdx.x * 4 + nl) * NPW;
    for (int ni = 0; ni < NPW; ++ni) {
        int node = node0 + ni;
        if (node >= N) break;
        long long base = (long long)node * DD;

        int beg = rowptr[node], end = rowptr[node + 1];
        float4 acc = make_float4(0.f, 0.f, 0.f, 0.f);
        int j = beg + eg;
        for (; j + 4 < end; j += 8) {
            int2 e0 = adj[j];
            int2 e1 = adj[j + 4];
            float4 v0 = h4[(long long)e0.x * 16 + q];
            float4 v1 = h4[(long long)e1.x * 16 + q];
            float w0 = __int_as_float(e0.y);
            float w1 = __int_as_float(e1.y);
            acc.x += w0 * v0.x + w1 * v1.x;
            acc.y += w0 * v0.y + w1 * v1.y;
            acc.z += w0 * v0.z + w1 * v1.z;
            acc.w += w0 * v0.w + w1 * v1.w;
        }
        if (j < end) {
            int2 e0 = adj[j];
            float4 v0 = h4[(long long)e0.x * 16 + q];
            float w0 = __int_as_float(e0.y);
            acc.x += w0 * v0.x;
            acc.y += w0 * v0.y;
            acc.z += w0 * v0.z;
            acc.w += w0 * v0.w;
        }
        // reduce across the 4 edge-slot groups (lanes q, q+16, q+32, q+48)
        #pragma unroll
        for (int m = 16; m < 64; m <<= 1) {
            acc.x += __shfl_xor(acc.x, m, 64);
            acc.y += __shfl_xor(acc.y, m, 64);
            acc.z += __shfl_xor(acc.z, m, 64);
            acc.w += __shfl_xor(acc.w, m, 64);
        }

        if (eg == 0) {
            float4 t0v = make_float4(0.f, 0.f, 0.f, 0.f);
            if (tx0) t0v = *reinterpret_cast<const float4*>(tx0 + base + q * 4);
            float4 v;
            v.x = scale * acc.x - t0v.x;
            v.y = scale * acc.y - t0v.y;
            v.z = scale * acc.z - t0v.z;
            v.w = scale * acc.w - t0v.w;
            if (txout) *reinterpret_cast<float4*>(txout + base + q * 4) = v;
            *reinterpret_cast<float4*>(&rows[nl][q * 4]) = v;
        }
        if (W0) xrow[nl][lane] = h[base + lane];   // h == x on the init pass
        __builtin_amdgcn_wave_barrier();           // pin LDS write->read ordering in-wave

        float o;
        if (W0) {
            o = bias[lane];
            #pragma unroll
            for (int jj = 0; jj < DD; ++jj) {
                o += xrow[nl][jj] * W0s[jj * DD + lane];
                o += rows[nl][jj] * Ws[jj * DD + lane];
            }
        } else {
            o = out[base + lane];
            #pragma unroll
            for (int jj = 0; jj < DD; ++jj) o += rows[nl][jj] * Ws[jj * DD + lane];
        }
        out[base + lane] = o;
        __builtin_amdgcn_wave_barrier();           // rows[] reused next node
    }
}

extern "C" void kernel_launch(void* const* d_in, const int* in_sizes, int n_in,
                              void* d_out, int out_size, void* d_ws, size_t ws_size,
                              hipStream_t stream) {
    const float* x  = (const float*)d_in[0];
    const int*   ei = (const int*)d_in[1];
    const float* W  = (const float*)d_in[2];
    const float* b  = (const float*)d_in[3];
    float* out = (float*)d_out;

    const int N = in_sizes[0] / DD;
    const int E = in_sizes[1] / 2;
    const int K = in_sizes[2] / (DD * DD);
    const long long ND = (long long)N * DD;

    const int* src = ei;
    const int* dst = ei + E;

    float* ws    = (float*)d_ws;
    float* dis   = ws;                          // N floats
    int*   cnt   = (int*)(dis + N);             // N
    int*   fillc = cnt + N;                     // N
    int*   rowptr= fillc + N;                   // N+1
    int*   bsum  = rowptr + N + 1;              // 128
    int2*  adj   = (int2*)(bsum + 128);         // E (8B each, 8B-aligned)
    float* B1    = (float*)(adj + E);           // ND
    float* B2    = B1 + ND;                     // ND

    // zero dis, cnt, fillc in one memset (contiguous)
    hipMemsetAsync(dis, 0, (size_t)(3 * N) * sizeof(float), stream);

    degcnt_kernel<<<(E + 255) / 256, 256, 0, stream>>>(src, dst, dis, cnt, E);
    dis_kernel<<<(N + 255) / 256, 256, 0, stream>>>(dis, N);

    const int nb = (N + 1023) / 1024;           // <= 128 required
    scan1_kernel<<<nb, 1024, 0, stream>>>(cnt, rowptr, bsum, N);
    scan2_kernel<<<1, 128, 0, stream>>>(bsum, nb);
    scan3_kernel<<<(N + 255) / 256, 256, 0, stream>>>(rowptr, bsum, N, E);
    fill_kernel<<<(E + 255) / 256, 256, 0, stream>>>(src, dst, dis, rowptr, fillc,
                                                     adj, E);

    const int pgrid = (N + 4 * NPW - 1) / (4 * NPW);
    const size_t lds1 = 2 * DD * DD * sizeof(float);  // init pass: Wk + W0
    const size_t ldsk = DD * DD * sizeof(float);      // later passes: Wk only

    // k=0 + k=1 fused: out = b + x@W0 + Tx1@W1 ; B1 = Tx1 = prop(x)
    prop_fused_kernel<<<pgrid, 256, lds1, stream>>>(rowptr, adj, x,
                                                    nullptr, W, W + DD * DD, b,
                                                    B1, out, 1.0f, N);

    // k>=2: Txk = 2*prop(Tx1) - Tx0 ; out += Txk@Wk
    // Rotation invariant: target always aliases the NEXT tx0 (safe: tx0 is
    // read only at the owning thread's index before the write); never aliases h.
    const float* t0 = x;
    float* t1 = B1;
    float* tg = B2;
    for (int k = 2; k < K; ++k) {
        float* txw = (k == K - 1) ? nullptr : tg;   // last Tx is never read
        prop_fused_kernel<<<pgrid, 256, ldsk, stream>>>(rowptr, adj, t1,
                                                        t0, nullptr,
                                                        W + (long long)k * DD * DD, b,
                                                        txw, out, 2.0f, N);
        const float* nt0 = t1;   // Tx_{k-1}
        float* nt1 = tg;         // Tx_k
        tg = (float*)nt0;        // next target aliases next tx0
        t0 = nt0;
        t1 = nt1;
    }
}